// Round 1
// baseline (137.012 us; speedup 1.0000x reference)
//
#include <hip/hip_runtime.h>

// Rowwise cosine similarity: out[r] = dot(a_r, b_r) * rsqrt(max(|a_r|^2,eps)) * rsqrt(max(|b_r|^2,eps))
// a, b: [16, 4096, 256] f32 contiguous -> 65536 rows of 256 floats.
// One 64-lane wave per row; each lane owns one float4 (4 elems * 64 lanes = 256).

#define D 256
#define EPS 1e-12f

__global__ __launch_bounds__(256) void cosine_rows_kernel(
    const float* __restrict__ a,
    const float* __restrict__ b,
    float* __restrict__ out,
    int n_rows)
{
    const int lane = threadIdx.x & 63;
    const int wave = threadIdx.x >> 6;            // 4 waves per block
    const int row  = blockIdx.x * 4 + wave;
    if (row >= n_rows) return;

    const float4* a4 = reinterpret_cast<const float4*>(a + (size_t)row * D);
    const float4* b4 = reinterpret_cast<const float4*>(b + (size_t)row * D);

    float4 av = a4[lane];
    float4 bv = b4[lane];

    float sa  = av.x * av.x + av.y * av.y + av.z * av.z + av.w * av.w;
    float sb  = bv.x * bv.x + bv.y * bv.y + bv.z * bv.z + bv.w * bv.w;
    float sab = av.x * bv.x + av.y * bv.y + av.z * bv.z + av.w * bv.w;

    // 64-lane butterfly reduction (wave = 64 on CDNA)
    #pragma unroll
    for (int off = 32; off > 0; off >>= 1) {
        sa  += __shfl_xor(sa,  off, 64);
        sb  += __shfl_xor(sb,  off, 64);
        sab += __shfl_xor(sab, off, 64);
    }

    if (lane == 0) {
        out[row] = sab * rsqrtf(fmaxf(sa, EPS)) * rsqrtf(fmaxf(sb, EPS));
    }
}

extern "C" void kernel_launch(void* const* d_in, const int* in_sizes, int n_in,
                              void* d_out, int out_size, void* d_ws, size_t ws_size,
                              hipStream_t stream)
{
    const float* a = (const float*)d_in[0];
    const float* b = (const float*)d_in[1];
    float* out = (float*)d_out;

    const int n_rows = out_size;            // 16 * 4096 = 65536
    const int rows_per_block = 4;           // 256 threads = 4 waves
    const int grid = (n_rows + rows_per_block - 1) / rows_per_block;

    cosine_rows_kernel<<<grid, 256, 0, stream>>>(a, b, out, n_rows);
}